// Round 1
// baseline (4981.419 us; speedup 1.0000x reference)
//
#include <hip/hip_runtime.h>
#include <math.h>

// ---------- constants ----------
#define Bc 4
#define Mc 4
#define Tc 128
#define Ec 512
#define Sc 512          // M*T
#define Hc 2048
#define NEc 8
#define NSc 2
#define TOPKc 2
#define NHEADc 4
#define Pc 128
#define GRUHc 128
#define AKc 64
#define AVc 64
#define NTc 2048        // B*S
#define HDc 128         // E/NHEAD

// ---------------------------------------------------------------
// zero out region + counters
__global__ __launch_bounds__(256)
void zero_k(float* __restrict__ out, int* __restrict__ cnt)
{
    int i = blockIdx.x * 256 + threadIdx.x;
    float4* o4 = (float4*)out;
    if (i < (NTc * Ec) / 4) o4[i] = make_float4(0.f, 0.f, 0.f, 0.f);
    if (i < NEc) cnt[i] = 0;
}

// ---------------------------------------------------------------
// generic fp32 tiled GEMM:  C = relu?( alpha*(A@B) + bias )
// optional: row gather on A, dynamic M/N/K from device pointers,
// B stored transposed, scatter-add epilogue (out[list[r]] += v*w).
__global__ __launch_bounds__(256)
void gemm_k(const float* __restrict__ A, int lda,
            const float* __restrict__ B, int ldb, int btrans,
            const float* __restrict__ bias,
            float* __restrict__ C, int ldc,
            int M, int N, int K,
            const int* __restrict__ Mptr, const int* __restrict__ Nptr,
            const int* __restrict__ Kptr,
            const int* __restrict__ gatherA,
            float alpha, int relu,
            float* __restrict__ scatterOut,
            const int* __restrict__ scatterList,
            const float* __restrict__ wvec)
{
    if (Mptr) M = *Mptr;
    if (Nptr) N = *Nptr;
    if (Kptr) K = *Kptr;
    int tm = blockIdx.x * 64, tn = blockIdx.y * 64;
    if (tm >= M || tn >= N) return;

    __shared__ float As[16][68];   // [k][row], padded for alignment
    __shared__ float Bs[16][68];   // [k][col]
    int tid = threadIdx.x;
    int tx = tid & 15, ty = tid >> 4;
    float acc[4][4] = {};

    int arow = tid >> 2;          // 0..63
    int ak0  = (tid & 3) * 4;     // 0,4,8,12
    int bk   = tid >> 4;          // 0..15
    int bc0  = (tid & 15) * 4;    // 0..60

    int grA = tm + arow;
    int gaRow = (grA < M) ? (gatherA ? gatherA[grA] : grA) : -1;
    const float* Arow = (gaRow >= 0) ? (A + (size_t)gaRow * lda) : nullptr;

    for (int k0 = 0; k0 < K; k0 += 16) {
#pragma unroll
        for (int u = 0; u < 4; ++u) {
            int k = k0 + ak0 + u;
            As[ak0 + u][arow] = (Arow && k < K) ? Arow[k] : 0.f;
        }
        int kb = k0 + bk;
#pragma unroll
        for (int u = 0; u < 4; ++u) {
            int n2 = tn + bc0 + u;
            float v = 0.f;
            if (kb < K && n2 < N)
                v = btrans ? B[(size_t)n2 * ldb + kb] : B[(size_t)kb * ldb + n2];
            Bs[bk][bc0 + u] = v;
        }
        __syncthreads();
#pragma unroll
        for (int kk = 0; kk < 16; ++kk) {
            float a0 = As[kk][ty * 4 + 0];
            float a1 = As[kk][ty * 4 + 1];
            float a2 = As[kk][ty * 4 + 2];
            float a3 = As[kk][ty * 4 + 3];
            float b0 = Bs[kk][tx * 4 + 0];
            float b1 = Bs[kk][tx * 4 + 1];
            float b2 = Bs[kk][tx * 4 + 2];
            float b3 = Bs[kk][tx * 4 + 3];
            acc[0][0] += a0 * b0; acc[0][1] += a0 * b1; acc[0][2] += a0 * b2; acc[0][3] += a0 * b3;
            acc[1][0] += a1 * b0; acc[1][1] += a1 * b1; acc[1][2] += a1 * b2; acc[1][3] += a1 * b3;
            acc[2][0] += a2 * b0; acc[2][1] += a2 * b1; acc[2][2] += a2 * b2; acc[2][3] += a2 * b3;
            acc[3][0] += a3 * b0; acc[3][1] += a3 * b1; acc[3][2] += a3 * b2; acc[3][3] += a3 * b3;
        }
        __syncthreads();
    }

#pragma unroll
    for (int i = 0; i < 4; ++i) {
        int gr = tm + ty * 4 + i;
        if (gr >= M) continue;
#pragma unroll
        for (int j = 0; j < 4; ++j) {
            int gc = tn + tx * 4 + j;
            if (gc >= N) continue;
            float v = acc[i][j] * alpha + (bias ? bias[gc] : 0.f);
            if (relu) v = fmaxf(v, 0.f);
            if (scatterOut) {
                int g = scatterList[gr];
                scatterOut[(size_t)g * Ec + gc] += v * wvec[(size_t)g * NEc];
            } else {
                C[(size_t)gr * ldc + gc] = v;
            }
        }
    }
}

// ---------------------------------------------------------------
// router 3-key attention -> ctx [2048,64]; one wave per token
__global__ __launch_bounds__(256)
void router_ctx_k(const float* __restrict__ q4, const float* __restrict__ rR,
                  const float* __restrict__ rS,
                  const float* __restrict__ Wk, const float* __restrict__ bk,
                  const float* __restrict__ Wv, const float* __restrict__ bv,
                  float* __restrict__ ctx)
{
    int tid = threadIdx.x;
    int lane = tid & 63;
    int n = blockIdx.x * 4 + (tid >> 6);
    int m = (n >> 7) & 3, t = n & 127, b = n >> 9;
    float q = q4[(size_t)n * AKc + lane];
    float sc[3], rv[3], sv[3];
#pragma unroll
    for (int o = 0; o < 3; ++o) {
        int oth = o + (o >= m ? 1 : 0);
        float r = rR[(((size_t)(b * Mc + m)) * Mc + oth) * Tc + t];
        float s_ = rS[(((size_t)(b * Mc + m)) * Mc + oth) * Tc + t];
        rv[o] = r; sv[o] = s_;
        float key = r * Wk[lane] + s_ * Wk[64 + lane] + bk[lane];
        float p = q * key;
#pragma unroll
        for (int off = 32; off; off >>= 1) p += __shfl_xor(p, off, 64);
        sc[o] = p * 0.125f;   // 1/sqrt(AK=64)
    }
    float mx = fmaxf(sc[0], fmaxf(sc[1], sc[2]));
    float e0 = expf(sc[0] - mx), e1 = expf(sc[1] - mx), e2 = expf(sc[2] - mx);
    float inv = 1.f / (e0 + e1 + e2);
    float p0 = e0 * inv, p1 = e1 * inv, p2 = e2 * inv;
    float v0 = rv[0] * Wv[lane] + sv[0] * Wv[64 + lane] + bv[lane];
    float v1 = rv[1] * Wv[lane] + sv[1] * Wv[64 + lane] + bv[lane];
    float v2 = rv[2] * Wv[lane] + sv[2] * Wv[64 + lane] + bv[lane];
    ctx[(size_t)n * AVc + lane] = p0 * v0 + p1 * v1 + p2 * v2;
}

// ---------------------------------------------------------------
// gi = gin @ gWih^T + gbih, gin = [rU, ctx] (65 features)
__global__ __launch_bounds__(256)
void gi_k(const float* __restrict__ rU, const float* __restrict__ ctx,
          const float* __restrict__ gWih, const float* __restrict__ gbih,
          float* __restrict__ gi)
{
    int idx = blockIdx.x * 256 + threadIdx.x;   // < 2048*384
    int g = idx % 384, nt = idx / 384;
    const float* Wr = gWih + (size_t)g * 65;
    float a = gbih[g] + rU[nt] * Wr[0];
    const float* c = ctx + (size_t)nt * AVc;
#pragma unroll
    for (int d = 0; d < 64; ++d) a += c[d] * Wr[1 + d];
    gi[(size_t)nt * 384 + g] = a;
}

// transpose gWhh [384,128] -> WhhT [128,384]
__global__ __launch_bounds__(256)
void whht_k(const float* __restrict__ gWhh, float* __restrict__ WhhT)
{
    int idx = blockIdx.x * 256 + threadIdx.x;  // < 49152
    int g = idx % 384, d = idx / 384;
    WhhT[(size_t)d * 384 + g] = gWhh[(size_t)g * 128 + d];
}

// GRU scan: one block per sequence (16), 384 threads
__global__ __launch_bounds__(384)
void gru_scan_k(const float* __restrict__ gi, const float* __restrict__ WhhT,
                const float* __restrict__ gbhh, float* __restrict__ hs)
{
    int seq = blockIdx.x, g = threadIdx.x;
    __shared__ float h[128];
    __shared__ float gh[384];
    if (g < 128) h[g] = 0.f;
    __syncthreads();
    for (int t = 0; t < 128; ++t) {
        float a = gbhh[g];
#pragma unroll 4
        for (int d = 0; d < 128; ++d) a += h[d] * WhhT[(size_t)d * 384 + g];
        gh[g] = a;
        __syncthreads();
        if (g < 128) {
            const float* gr = gi + ((size_t)seq * 128 + t) * 384;
            float r = 1.f / (1.f + expf(-(gr[g] + gh[g])));
            float z = 1.f / (1.f + expf(-(gr[128 + g] + gh[128 + g])));
            float nn = tanhf(gr[256 + g] + r * gh[256 + g]);
            float hn = (1.f - z) * nn + z * h[g];
            hs[((size_t)seq * 128 + t) * 128 + g] = hn;
            h[g] = hn;
        }
        __syncthreads();
    }
}

// ---------------------------------------------------------------
// router MLP + softmax + top-2 + weights. one block (128 thr) per token
__global__ __launch_bounds__(128)
void mlp_route_k(const float* __restrict__ proc, const float* __restrict__ hs,
                 const float* __restrict__ mW1, const float* __restrict__ mb1,
                 const float* __restrict__ mW2, const float* __restrict__ mb2,
                 float* __restrict__ probsOut, float* __restrict__ idxOut,
                 float* __restrict__ w)
{
    int n = blockIdx.x, tid = threadIdx.x;
    __shared__ float comb[256], tmp[128], lg[8];
    comb[tid] = proc[(size_t)n * 128 + tid];
    comb[128 + tid] = hs[(size_t)n * 128 + tid];
    __syncthreads();
    float a = mb1[tid];
#pragma unroll 8
    for (int d = 0; d < 256; ++d) a += comb[d] * mW1[(size_t)d * 128 + tid];
    tmp[tid] = fmaxf(a, 0.f);
    __syncthreads();
    if (tid < 8) {
        float l = mb2[tid];
        for (int d = 0; d < 128; ++d) l += tmp[d] * mW2[(size_t)d * 8 + tid];
        lg[tid] = l;
    }
    __syncthreads();
    if (tid == 0) {
        float mx = lg[0];
        for (int e = 1; e < 8; ++e) mx = fmaxf(mx, lg[e]);
        float p[8], s = 0.f;
        for (int e = 0; e < 8; ++e) { p[e] = expf(lg[e] - mx); s += p[e]; }
        float inv = 1.f / s;
        for (int e = 0; e < 8; ++e) probsOut[(size_t)n * 8 + e] = p[e] * inv;
        int a0 = 0; float v0 = lg[0];
        for (int e = 1; e < 8; ++e) if (lg[e] > v0) { v0 = lg[e]; a0 = e; }
        int a1 = -1; float v1 = -1e30f;
        for (int e = 0; e < 8; ++e) if (e != a0 && lg[e] > v1) { v1 = lg[e]; a1 = e; }
        float e1 = expf(v1 - v0);
        float t0 = 1.f / (1.f + e1), t1 = e1 / (1.f + e1);
        idxOut[(size_t)n * 2 + 0] = (float)a0;
        idxOut[(size_t)n * 2 + 1] = (float)a1;
        for (int e = 0; e < 8; ++e) w[(size_t)n * 8 + e] = 0.f;
        w[(size_t)n * 8 + a0] = t0;
        w[(size_t)n * 8 + a1] = t1;
    }
}

// compaction: build per-expert token lists
__global__ __launch_bounds__(256)
void compact_k(const float* __restrict__ w, int* __restrict__ cnt,
               int* __restrict__ list)
{
    int n = blockIdx.x * 256 + threadIdx.x;
    if (n >= NTc) return;
    for (int e = 0; e < NEc; ++e)
        if (w[(size_t)n * 8 + e] > 0.f) {
            int p = atomicAdd(&cnt[e], 1);
            list[e * NTc + p] = n;
        }
}

// ---------------------------------------------------------------
// softmax over rows of S (in place), row i valid cols j<cnt
__global__ __launch_bounds__(256)
void softmax_rows_k(float* __restrict__ S, const int* __restrict__ cntPtr)
{
    int nv = *cntPtr;
    int i = blockIdx.x;
    if (i >= nv) return;
    float* row = S + (size_t)i * NTc;
    int tid = threadIdx.x;
    __shared__ float red[256];
    float mx = -1e30f;
    for (int j = tid; j < nv; j += 256) mx = fmaxf(mx, row[j]);
    red[tid] = mx; __syncthreads();
    for (int st = 128; st > 0; st >>= 1) { if (tid < st) red[tid] = fmaxf(red[tid], red[tid + st]); __syncthreads(); }
    mx = red[0]; __syncthreads();
    float sum = 0.f;
    for (int j = tid; j < nv; j += 256) { float e = expf(row[j] - mx); row[j] = e; sum += e; }
    red[tid] = sum; __syncthreads();
    for (int st = 128; st > 0; st >>= 1) { if (tid < st) red[tid] += red[tid + st]; __syncthreads(); }
    float inv = 1.f / red[0];
    for (int j = tid; j < nv; j += 256) row[j] *= inv;
}

// LN( x[list[i]] + add[i] ) -> outRows[i]
__global__ __launch_bounds__(256)
void ln1_k(const float* __restrict__ x, const int* __restrict__ list,
           const float* __restrict__ add, const float* __restrict__ s,
           const float* __restrict__ b, float* __restrict__ outRows,
           const int* __restrict__ cntPtr)
{
    int i = blockIdx.x;
    if (i >= *cntPtr) return;
    int tid = threadIdx.x;
    int g = list[i];
    float v0 = x[(size_t)g * Ec + tid] + add[(size_t)i * Ec + tid];
    float v1 = x[(size_t)g * Ec + 256 + tid] + add[(size_t)i * Ec + 256 + tid];
    __shared__ float red[256];
    __shared__ float bc;
    red[tid] = v0 + v1; __syncthreads();
    for (int st = 128; st > 0; st >>= 1) { if (tid < st) red[tid] += red[tid + st]; __syncthreads(); }
    if (tid == 0) bc = red[0] * (1.f / 512.f);
    __syncthreads();
    float mu = bc;
    float d0 = v0 - mu, d1 = v1 - mu;
    __syncthreads();
    red[tid] = d0 * d0 + d1 * d1; __syncthreads();
    for (int st = 128; st > 0; st >>= 1) { if (tid < st) red[tid] += red[tid + st]; __syncthreads(); }
    if (tid == 0) bc = rsqrtf(red[0] * (1.f / 512.f) + 1e-5f);
    __syncthreads();
    float inv = bc;
    outRows[(size_t)i * Ec + tid] = d0 * inv * s[tid] + b[tid];
    outRows[(size_t)i * Ec + 256 + tid] = d1 * inv * s[256 + tid] + b[256 + tid];
}

// LN( H1[i] + Y[i] ) * w -> out[list[i]] +=
__global__ __launch_bounds__(256)
void ln2_scatter_k(const float* __restrict__ H1, const float* __restrict__ Y,
                   const float* __restrict__ s, const float* __restrict__ b,
                   float* __restrict__ out, const int* __restrict__ list,
                   const int* __restrict__ cntPtr, const float* __restrict__ wvec)
{
    int i = blockIdx.x;
    if (i >= *cntPtr) return;
    int tid = threadIdx.x;
    int g = list[i];
    float v0 = H1[(size_t)i * Ec + tid] + Y[(size_t)i * Ec + tid];
    float v1 = H1[(size_t)i * Ec + 256 + tid] + Y[(size_t)i * Ec + 256 + tid];
    __shared__ float red[256];
    __shared__ float bc;
    red[tid] = v0 + v1; __syncthreads();
    for (int st = 128; st > 0; st >>= 1) { if (tid < st) red[tid] += red[tid + st]; __syncthreads(); }
    if (tid == 0) bc = red[0] * (1.f / 512.f);
    __syncthreads();
    float mu = bc;
    float d0 = v0 - mu, d1 = v1 - mu;
    __syncthreads();
    red[tid] = d0 * d0 + d1 * d1; __syncthreads();
    for (int st = 128; st > 0; st >>= 1) { if (tid < st) red[tid] += red[tid + st]; __syncthreads(); }
    if (tid == 0) bc = rsqrtf(red[0] * (1.f / 512.f) + 1e-5f);
    __syncthreads();
    float inv = bc;
    float wv = wvec[(size_t)g * 8];
    out[(size_t)g * Ec + tid] += (d0 * inv * s[tid] + b[tid]) * wv;
    out[(size_t)g * Ec + 256 + tid] += (d1 * inv * s[256 + tid] + b[256 + tid]) * wv;
}

// ---------------------------------------------------------------
static inline void gemm(hipStream_t st, int gx, int gy,
                        const float* A, int lda, const float* B, int ldb, int btrans,
                        const float* bias, float* C, int ldc,
                        int M, int N, int K,
                        const int* Mptr, const int* Nptr, const int* Kptr,
                        const int* gatherA, float alpha, int relu,
                        float* scOut, const int* scList, const float* wv)
{
    gemm_k<<<dim3(gx, gy), 256, 0, st>>>(A, lda, B, ldb, btrans, bias, C, ldc,
                                         M, N, K, Mptr, Nptr, Kptr, gatherA,
                                         alpha, relu, scOut, scList, wv);
}

extern "C" void kernel_launch(void* const* d_in, const int* in_sizes, int n_in,
                              void* d_out, int out_size, void* d_ws, size_t ws_size,
                              hipStream_t stream)
{
    const float* x    = (const float*)d_in[0];
    const float* rU   = (const float*)d_in[1];
    const float* rR   = (const float*)d_in[2];
    const float* rS   = (const float*)d_in[3];
    const float* Wtp  = (const float*)d_in[6];
    const float* btp  = (const float*)d_in[7];
    const float* Wq   = (const float*)d_in[8];
    const float* bq   = (const float*)d_in[9];
    const float* Wk   = (const float*)d_in[10];
    const float* bk   = (const float*)d_in[11];
    const float* Wv   = (const float*)d_in[12];
    const float* bv   = (const float*)d_in[13];
    const float* gWih = (const float*)d_in[14];
    const float* gbih = (const float*)d_in[15];
    const float* gWhh = (const float*)d_in[16];
    const float* gbhh = (const float*)d_in[17];
    const float* mW1  = (const float*)d_in[18];
    const float* mb1  = (const float*)d_in[19];
    const float* mW2  = (const float*)d_in[20];
    const float* mb2  = (const float*)d_in[21];
    const float* sWq  = (const float*)d_in[22];
    const float* sbq  = (const float*)d_in[23];
    const float* sWk  = (const float*)d_in[24];
    const float* sbk  = (const float*)d_in[25];
    const float* sWv  = (const float*)d_in[26];
    const float* sbv  = (const float*)d_in[27];
    const float* sWo  = (const float*)d_in[28];
    const float* sbo  = (const float*)d_in[29];
    const float* sln1s = (const float*)d_in[30];
    const float* sln1b = (const float*)d_in[31];
    const float* sW1  = (const float*)d_in[32];
    const float* sb1  = (const float*)d_in[33];
    const float* sW2  = (const float*)d_in[34];
    const float* sb2  = (const float*)d_in[35];
    const float* sln2s = (const float*)d_in[36];
    const float* sln2b = (const float*)d_in[37];
    const float* fW1  = (const float*)d_in[38];
    const float* fb1  = (const float*)d_in[39];
    const float* fW2  = (const float*)d_in[40];
    const float* fb2  = (const float*)d_in[41];

    float* out      = (float*)d_out;                 // [2048,512]
    float* probsOut = out + (size_t)NTc * Ec;        // [2048,8]
    float* idxOut   = probsOut + (size_t)NTc * NEc;  // [2048,2]

    // workspace layout
    int*   cnt  = (int*)d_ws;                 // 8 (padded to 64)
    int*   list = cnt + 64;                   // 8*2048
    float* w    = (float*)d_ws + 64 + NEc * NTc;  // [2048,8]
    float* B0   = w + NTc * NEc;
    // router region (dead before experts start)
    float* proc = B0;                  // 2048*128
    float* q4   = proc + 262144;       // 2048*64
    float* ctx  = q4 + 131072;         // 2048*64
    float* gi   = ctx + 131072;        // 16*128*384
    float* hs   = gi + 786432;         // 2048*128
    float* WhhT = hs + 262144;         // 128*384
    // expert region (overlays router region)
    float* S   = B0;                   // 2048*2048
    float* Qb  = S + 4194304;          // 2048*512
    float* Kb  = Qb + 1048576;
    float* Vb  = Kb + 1048576;
    float* AO  = Vb + 1048576;
    float* PRJ = AO + 1048576;
    float* H1  = PRJ + 1048576;
    float* Yb  = H1 + 1048576;
    float* FF1 = Yb + 1048576;         // 2048*2048

    const float invsq = 0.08838834764831845f;  // 1/sqrt(128)

    // ---- init ----
    zero_k<<<1024, 256, 0, stream>>>(out, cnt);

    // ---- router ----
    gemm(stream, 32, 2, x, Ec, Wtp, Pc, 0, btp, proc, Pc,
         NTc, Pc, Ec, nullptr, nullptr, nullptr, nullptr, 1.f, 1, nullptr, nullptr, nullptr);
    gemm(stream, 32, 1, proc, Pc, Wq, AKc, 0, bq, q4, AKc,
         NTc, AKc, Pc, nullptr, nullptr, nullptr, nullptr, 1.f, 0, nullptr, nullptr, nullptr);
    router_ctx_k<<<512, 256, 0, stream>>>(q4, rR, rS, Wk, bk, Wv, bv, ctx);
    whht_k<<<192, 256, 0, stream>>>(gWhh, WhhT);
    gi_k<<<3072, 256, 0, stream>>>(rU, ctx, gWih, gbih, gi);
    gru_scan_k<<<16, 384, 0, stream>>>(gi, WhhT, gbhh, hs);
    mlp_route_k<<<2048, 128, 0, stream>>>(proc, hs, mW1, mb1, mW2, mb2,
                                          probsOut, idxOut, w);
    compact_k<<<8, 256, 0, stream>>>(w, cnt, list);

    // ---- synergy experts ----
    for (int e = 0; e < NSc; ++e) {
        const int* cl = list + e * NTc;
        const int* ce = cnt + e;
        gemm(stream, 32, 8, x, Ec, sWq + (size_t)e * Ec * Ec, Ec, 0, sbq + e * Ec, Qb, Ec,
             NTc, Ec, Ec, ce, nullptr, nullptr, cl, 1.f, 0, nullptr, nullptr, nullptr);
        gemm(stream, 32, 8, x, Ec, sWk + (size_t)e * Ec * Ec, Ec, 0, sbk + e * Ec, Kb, Ec,
             NTc, Ec, Ec, ce, nullptr, nullptr, cl, 1.f, 0, nullptr, nullptr, nullptr);
        gemm(stream, 32, 8, x, Ec, sWv + (size_t)e * Ec * Ec, Ec, 0, sbv + e * Ec, Vb, Ec,
             NTc, Ec, Ec, ce, nullptr, nullptr, cl, 1.f, 0, nullptr, nullptr, nullptr);
        for (int h = 0; h < NHEADc; ++h) {
            gemm(stream, 32, 32, Qb + h * HDc, Ec, Kb + h * HDc, Ec, 1, nullptr, S, NTc,
                 NTc, NTc, HDc, ce, ce, nullptr, nullptr, invsq, 0, nullptr, nullptr, nullptr);
            softmax_rows_k<<<2048, 256, 0, stream>>>(S, ce);
            gemm(stream, 32, 2, S, NTc, Vb + h * HDc, Ec, 0, nullptr, AO + h * HDc, Ec,
                 NTc, HDc, NTc, ce, nullptr, ce, nullptr, 1.f, 0, nullptr, nullptr, nullptr);
        }
        gemm(stream, 32, 8, AO, Ec, sWo + (size_t)e * Ec * Ec, Ec, 0, sbo + e * Ec, PRJ, Ec,
             NTc, Ec, Ec, ce, nullptr, nullptr, nullptr, 1.f, 0, nullptr, nullptr, nullptr);
        ln1_k<<<2048, 256, 0, stream>>>(x, cl, PRJ, sln1s + e * Ec, sln1b + e * Ec, H1, ce);
        gemm(stream, 32, 32, H1, Ec, sW1 + (size_t)e * Ec * Hc, Hc, 0, sb1 + e * Hc, FF1, Hc,
             NTc, Hc, Ec, ce, nullptr, nullptr, nullptr, 1.f, 1, nullptr, nullptr, nullptr);
        gemm(stream, 32, 8, FF1, Hc, sW2 + (size_t)e * Hc * Ec, Ec, 0, sb2 + e * Ec, Yb, Ec,
             NTc, Ec, Hc, ce, nullptr, nullptr, nullptr, 1.f, 0, nullptr, nullptr, nullptr);
        ln2_scatter_k<<<2048, 256, 0, stream>>>(H1, Yb, sln2s + e * Ec, sln2b + e * Ec,
                                                out, cl, ce, w + e);
    }

    // ---- FFN experts ----
    for (int f = 0; f < NEc - NSc; ++f) {
        int e = f + NSc;
        const int* cl = list + e * NTc;
        const int* ce = cnt + e;
        gemm(stream, 32, 32, x, Ec, fW1 + (size_t)f * Ec * Hc, Hc, 0, fb1 + f * Hc, FF1, Hc,
             NTc, Hc, Ec, ce, nullptr, nullptr, cl, 1.f, 1, nullptr, nullptr, nullptr);
        gemm(stream, 32, 8, FF1, Hc, fW2 + (size_t)f * Hc * Ec, Ec, 0, fb2 + f * Ec,
             nullptr, Ec, NTc, Ec, Hc, ce, nullptr, nullptr, nullptr, 1.f, 0,
             out, cl, w + e);
    }
}